// Round 18
// baseline (214.786 us; speedup 1.0000x reference)
//
#include <hip/hip_runtime.h>
#include <hip/hip_bf16.h>
#include <math.h>

#define Bsz 512
#define Lm  128
#define Mn  6
#define AD  39
#define BDm 10
#define KN  49          // AD+BDm
#define F   256
#define TB  16
#define NR  96          // TB*Mn
#define NFP 264         // padded row stride (ushorts)
#define ANP 72          // staging row stride (ushorts), K padded to 64

// ws byte offsets
#define WS_WATM 0
#define WS_WNBR 32768
#define WS_WATT 65536
#define WS_WIH  196608
#define WS_WHH  589824
#define WS_WALN 983040
#define WS_SUM  991232
#define WS_AF   1253376
#define WS_WN   34807808

typedef __attribute__((ext_vector_type(8))) short bf16x8;
typedef __attribute__((ext_vector_type(4))) float f32x4;
typedef __attribute__((ext_vector_type(4))) unsigned int u32x4;

__device__ __forceinline__ float lrelu(float x){ return x > 0.0f ? x : 0.01f*x; }
__device__ __forceinline__ float sigm(float x){
    return __builtin_amdgcn_rcpf(1.0f + __expf(-x));
}
__device__ __forceinline__ float ftanh(float x){
    float xc = fminf(fmaxf(x, -15.f), 15.f);
    float e  = __expf(2.0f*xc);
    return 1.0f - 2.0f*__builtin_amdgcn_rcpf(e + 1.0f);
}
__device__ __forceinline__ float felu(float x){ return x > 0.f ? x : (__expf(x) - 1.0f); }

__device__ __forceinline__ unsigned short f2bfh(float f){
    __hip_bfloat16 h = __float2bfloat16(f);
    unsigned short s;
    __builtin_memcpy(&s, &h, 2);
    return s;
}
__device__ __forceinline__ unsigned int pack2bf(float lo, float hi){
    float2 f2; f2.x = lo; f2.y = hi;
    __hip_bfloat162 h2 = __float22bfloat162_rn(f2);
    unsigned int u;
    __builtin_memcpy(&u, &h2, 4);
    return u;
}
__device__ __forceinline__ float bf2f(unsigned short h){
    unsigned int u = ((unsigned int)h)<<16;
    return __builtin_bit_cast(float, u);
}

// ---------------- P0: weights -> bf16 fragment-major ----------------
__global__ __launch_bounds__(256)
void p0_prep(const float* __restrict__ Watm, const float* __restrict__ Wnbr,
             const float* __restrict__ Watt, const float* __restrict__ Wih,
             const float* __restrict__ Whh,  const float* __restrict__ Waln,
             unsigned short* __restrict__ ws)
{
    int id = blockIdx.x*256 + threadIdx.x;
    if (id >= 968*512) return;
    int T = id >> 9, e = id & 511;
    int lane = e >> 3, j = e & 7;
    int col16 = lane & 15, kg = lane >> 4;
    float v; unsigned short* dst;
    if (T < 32) {                 // W_atom [256][39], pad 64
        int nt = T >> 1, ks = T & 1;
        int k = ks*32 + kg*8 + j;
        v = (k < AD) ? Watm[(nt*16 + col16)*AD + k] : 0.0f;
        dst = ws + (WS_WATM>>1) + (size_t)T*512 + e;
    } else if (T < 64) {          // W_nbr [256][49], pad 64
        int T2 = T - 32;
        int nt = T2 >> 1, ks = T2 & 1;
        int k = ks*32 + kg*8 + j;
        v = (k < KN) ? Wnbr[(nt*16 + col16)*KN + k] : 0.0f;
        dst = ws + (WS_WNBR>>1) + (size_t)T2*512 + e;
    } else if (T < 192) {         // W_att [256][256]
        int T2 = T - 64;
        int nt = T2 >> 3, ks = T2 & 7;
        v = Watt[(nt*16 + col16)*F + ks*32 + kg*8 + j];
        dst = ws + (WS_WATT>>1) + (size_t)T2*512 + e;
    } else if (T < 576) {         // W_ih [768][256]
        int T3 = T - 192;
        int nt = T3 >> 3, ks = T3 & 7;
        v = Wih[(nt*16 + col16)*F + ks*32 + kg*8 + j];
        dst = ws + (WS_WIH>>1) + (size_t)T3*512 + e;
    } else if (T < 960) {         // W_hh [768][256]
        int T4 = T - 576;
        int nt = T4 >> 3, ks = T4 & 7;
        v = Whh[(nt*16 + col16)*F + ks*32 + kg*8 + j];
        dst = ws + (WS_WHH>>1) + (size_t)T4*512 + e;
    } else {                      // walign2 b-frag: col 0 = Walign[256+k]
        int ks = T - 960;
        v = (col16 == 0) ? Waln[F + ks*32 + kg*8 + j] : 0.0f;
        dst = ws + (WS_WALN>>1) + (size_t)ks*512 + e;
    }
    *dst = f2bfh(v);
}

// ---------------- K2: 8 waves; atom+neighbor MFMA, af store, MFMA nscore, softmax, wn ----------------
#define NT2 512
__global__ __launch_bounds__(NT2, 6)
void k2_nbr(const float* __restrict__ atom, const float* __restrict__ bond,
            const int* __restrict__ adeg_g, const int* __restrict__ bdeg_g,
            const float* __restrict__ Walign, const float* __restrict__ balign,
            const float* __restrict__ batom,  const float* __restrict__ bnbr,
            const unsigned short* __restrict__ ws,
            unsigned short* __restrict__ af_g,
            unsigned short* __restrict__ wn_g, float* __restrict__ sumaw_g)
{
    __shared__ alignas(16) unsigned short nfl[NR*NFP];   // staging overlaid
    __shared__ float ascl[TB];
    __shared__ float nscl[NR];
    __shared__ float awl[NR];
    __shared__ int   adeg[NR];
    __shared__ int   bdeg[NR];
    unsigned short* stg = nfl;   // [112][ANP]: rows 0-15 own atoms, 16-111 neighbors

    const int t  = threadIdx.x;
    const int g0 = blockIdx.x*TB;
    const int molbase = (g0/Lm)*Lm;
    const int w = t >> 6, lane = t & 63;
    const int col16 = lane & 15, kg = lane >> 4;

    bf16x8 batmf[2][2], bnbrf[2][2];   // [j][ks]
    #pragma unroll
    for (int j = 0; j < 2; ++j)
        #pragma unroll
        for (int ks = 0; ks < 2; ++ks) {
            batmf[j][ks] = *(const bf16x8*)&ws[(WS_WATM>>1) + (size_t)((2*w+j)*2 + ks)*512 + lane*8];
            bnbrf[j][ks] = *(const bf16x8*)&ws[(WS_WNBR>>1) + (size_t)((2*w+j)*2 + ks)*512 + lane*8];
        }

    if (t < NR) {
        adeg[t] = adeg_g[(size_t)g0*Mn + t];
        bdeg[t] = bdeg_g[(size_t)g0*Mn + t];
    }
    if (t < TB) ascl[t] = 0.f;
    __syncthreads();   // B0

    for (int i = t; i < 112*32; i += NT2) {
        int r = i >> 5, d0 = (i & 31)*2;
        float v0, v1;
        if (r < TB) {
            const float* src = atom + (size_t)(g0+r)*AD;
            v0 = (d0   < AD) ? src[d0]   : 0.f;
            v1 = (d0+1 < AD) ? src[d0+1] : 0.f;
        } else {
            int rr = r - TB;
            const float* asrc = atom + (size_t)(molbase + adeg[rr])*AD;
            const float* bsrc = bond + (size_t)(molbase + bdeg[rr])*BDm;
            int d1 = d0+1;
            v0 = (d0 < AD) ? asrc[d0] : ((d0 < KN) ? bsrc[d0-AD] : 0.f);
            v1 = (d1 < AD) ? asrc[d1] : ((d1 < KN) ? bsrc[d1-AD] : 0.f);
        }
        *(unsigned int*)&stg[r*ANP + d0] = pack2bf(v0, v1);
    }
    __syncthreads();   // B1

    // ---- atom MFMA -> af (global bf16, cached: k4 re-reads it) + ascore
    {
        f32x4 acc[2];
        #pragma unroll
        for (int j = 0; j < 2; ++j) acc[j] = (f32x4){0.f,0.f,0.f,0.f};
        #pragma unroll
        for (int ks = 0; ks < 2; ++ks) {
            bf16x8 a = *(const bf16x8*)&stg[col16*ANP + ks*32 + kg*8];
            #pragma unroll
            for (int j = 0; j < 2; ++j)
                acc[j] = __builtin_amdgcn_mfma_f32_16x16x32_bf16(a, batmf[j][ks], acc[j], 0, 0, 0);
        }
        float ps[4] = {0.f,0.f,0.f,0.f};
        #pragma unroll
        for (int j = 0; j < 2; ++j) {
            const int col = (2*w+j)*16 + col16;
            const float bb  = batom[col];
            const float wal = Walign[col];
            #pragma unroll
            for (int jj = 0; jj < 4; ++jj) {
                float v = lrelu(acc[j][jj] + bb);
                af_g[(size_t)(g0 + kg*4 + jj)*F + col] = f2bfh(v);
                ps[jj] += v*wal;
            }
        }
        #pragma unroll
        for (int jj = 0; jj < 4; ++jj) {
            float p = ps[jj];
            p += __shfl_xor(p, 1); p += __shfl_xor(p, 2);
            p += __shfl_xor(p, 4); p += __shfl_xor(p, 8);
            if (col16 == 0) atomicAdd(&ascl[kg*4 + jj], p);
        }
    }

    // ---- neighbor MFMA
    f32x4 acc[6][2];
    #pragma unroll
    for (int mt = 0; mt < 6; ++mt)
        #pragma unroll
        for (int j = 0; j < 2; ++j) acc[mt][j] = (f32x4){0.f,0.f,0.f,0.f};
    #pragma unroll
    for (int ks = 0; ks < 2; ++ks) {
        #pragma unroll
        for (int mt = 0; mt < 6; ++mt) {
            bf16x8 a = *(const bf16x8*)&stg[(TB + mt*16 + col16)*ANP + ks*32 + kg*8];
            #pragma unroll
            for (int j = 0; j < 2; ++j)
                acc[mt][j] = __builtin_amdgcn_mfma_f32_16x16x32_bf16(a, bnbrf[j][ks], acc[mt][j], 0, 0, 0);
        }
    }
    __syncthreads();   // B2

    #pragma unroll
    for (int mt = 0; mt < 6; ++mt)
        #pragma unroll
        for (int j = 0; j < 2; ++j) {
            const int col = (2*w+j)*16 + col16;
            const float bnb = bnbr[col];
            #pragma unroll
            for (int jj = 0; jj < 4; ++jj)
                nfl[(mt*16 + kg*4 + jj)*NFP + col] = f2bfh(lrelu(acc[mt][j][jj] + bnb));
        }
    __syncthreads();   // B3

    // ---- nscore via MFMA (B col0-only frag); waves 0..5
    if (w < 6) {
        const int mt = w;
        f32x4 ns = {0.f,0.f,0.f,0.f};
        #pragma unroll
        for (int ks = 0; ks < 8; ++ks) {
            bf16x8 a = *(const bf16x8*)&nfl[(mt*16 + col16)*NFP + ks*32 + kg*8];
            bf16x8 b = *(const bf16x8*)&ws[(WS_WALN>>1) + (size_t)ks*512 + lane*8];
            ns = __builtin_amdgcn_mfma_f32_16x16x32_bf16(a, b, ns, 0, 0, 0);
        }
        if (col16 == 0) {
            #pragma unroll
            for (int jj = 0; jj < 4; ++jj) nscl[mt*16 + kg*4 + jj] = ns[jj];
        }
    }
    __syncthreads();   // B4

    if (t < TB) {
        const float ba = balign[0];
        const float as = ascl[t];
        float sc[Mn], msk[Mn];
        float mx = -1e30f;
        #pragma unroll
        for (int m = 0; m < Mn; ++m) {
            int pad = (adeg[t*Mn+m] == Lm-1);
            float s = lrelu(as + nscl[t*Mn+m] + ba) + (pad ? -9e8f : 0.0f);
            msk[m] = pad ? 0.f : 1.f;
            sc[m] = s; mx = fmaxf(mx, s);
        }
        float sum = 0.f;
        #pragma unroll
        for (int m = 0; m < Mn; ++m) { sc[m] = __expf(sc[m]-mx); sum += sc[m]; }
        const float inv = __builtin_amdgcn_rcpf(sum);
        float sa = 0.f;
        #pragma unroll
        for (int m = 0; m < Mn; ++m) { float v = sc[m]*inv*msk[m]; awl[t*Mn+m] = v; sa += v; }
        sumaw_g[g0 + t] = sa;
    }
    __syncthreads();   // B5

    // wn[a][:] = sum_m aw*nf  (nt store: read exactly once by k4 phase1)
    {
        const int a = t & 15, cg = t >> 4;
        float o[8] = {0,0,0,0,0,0,0,0};
        #pragma unroll
        for (int m = 0; m < Mn; ++m) {
            const float aw = awl[a*Mn + m];
            u32x4 v = *(const u32x4*)&nfl[(a*Mn+m)*NFP + cg*8];
            o[0] += aw*__builtin_bit_cast(float, v.x<<16);
            o[1] += aw*__builtin_bit_cast(float, v.x & 0xffff0000u);
            o[2] += aw*__builtin_bit_cast(float, v.y<<16);
            o[3] += aw*__builtin_bit_cast(float, v.y & 0xffff0000u);
            o[4] += aw*__builtin_bit_cast(float, v.z<<16);
            o[5] += aw*__builtin_bit_cast(float, v.z & 0xffff0000u);
            o[6] += aw*__builtin_bit_cast(float, v.w<<16);
            o[7] += aw*__builtin_bit_cast(float, v.w & 0xffff0000u);
        }
        u32x4 pv;
        pv.x = pack2bf(o[0], o[1]);
        pv.y = pack2bf(o[2], o[3]);
        pv.z = pack2bf(o[4], o[5]);
        pv.w = pack2bf(o[6], o[7]);
        __builtin_nontemporal_store(pv, (u32x4*)&wn_g[(size_t)(g0+a)*F + cg*8]);
    }
}

// ---------------- K4: ctx GEMM + q-split GRU GEMM + gates (LDS diet: no afl) ----------------
// af is read from global (L2/L3-cached) as phase-2 A-frags + epilogue blend;
// LDS = wnl only (34 KB) -> 3-4 blocks/CU instead of 2 (the 40% stall was
// latency with too few waves). q-split + unroll-1 keeps live B-frags bounded
// (no spill). NO min-waves bound (R6/R9); NO full unroll (R11/R12).
#define NTK4 512
#define K4A  64
__global__ __launch_bounds__(NTK4)
void k4_gru(const unsigned short* __restrict__ ws,
            const unsigned short* __restrict__ wn_g,
            const unsigned short* __restrict__ af_g,
            const float* __restrict__ sumaw_g,
            const float* __restrict__ batt,
            const float* __restrict__ bih, const float* __restrict__ bhh,
            float* __restrict__ out)
{
    __shared__ alignas(16) unsigned short wnl[K4A*NFP];   // ctxl overlays after phase1
    __shared__ float sumawl[K4A];
    const int t  = threadIdx.x;
    const int g0 = blockIdx.x*K4A;

    for (int i = t; i < K4A*32; i += NTK4) {
        int row = i >> 5, cg = i & 31;
        u32x4 v = __builtin_nontemporal_load((const u32x4*)&wn_g[(size_t)(g0+row)*F + cg*8]);
        *(u32x4*)&wnl[row*NFP + cg*8] = v;
    }
    if (t < K4A) sumawl[t] = sumaw_g[g0 + t];
    __syncthreads();   // B1

    const int w = t >> 6, lane = t & 63;
    const int col16 = lane & 15, kg = lane >> 4;
    const unsigned short* wsAtt = ws + (WS_WATT>>1);
    const unsigned short* wsIh  = ws + (WS_WIH>>1);
    const unsigned short* wsHh  = ws + (WS_WHH>>1);
    const unsigned short* afb   = af_g + (size_t)g0*F;

    // ---- phase 1: ctx = elu(wn @ Watt^T + b_att*sumaw); wave w -> nt {2w, 2w+1}
    f32x4 c0[4], c1[4];
    {
        const float bb0 = batt[(2*w)*16   + col16];
        const float bb1 = batt[(2*w+1)*16 + col16];
        #pragma unroll
        for (int mt = 0; mt < 4; ++mt)
            #pragma unroll
            for (int jj = 0; jj < 4; ++jj) {
                float sa = sumawl[mt*16 + kg*4 + jj];
                c0[mt][jj] = bb0*sa; c1[mt][jj] = bb1*sa;
            }
        #pragma unroll 2
        for (int ks = 0; ks < 8; ++ks) {
            bf16x8 b0 = *(const bf16x8*)&wsAtt[(size_t)((2*w)*8   + ks)*512 + lane*8];
            bf16x8 b1 = *(const bf16x8*)&wsAtt[(size_t)((2*w+1)*8 + ks)*512 + lane*8];
            #pragma unroll
            for (int mt = 0; mt < 4; ++mt) {
                bf16x8 a = *(const bf16x8*)&wnl[(mt*16 + col16)*NFP + ks*32 + kg*8];
                c0[mt] = __builtin_amdgcn_mfma_f32_16x16x32_bf16(a, b0, c0[mt], 0, 0, 0);
                c1[mt] = __builtin_amdgcn_mfma_f32_16x16x32_bf16(a, b1, c1[mt], 0, 0, 0);
            }
        }
    }
    __syncthreads();   // B2
    unsigned short* ctxl = wnl;
    #pragma unroll
    for (int mt = 0; mt < 4; ++mt)
        #pragma unroll
        for (int jj = 0; jj < 4; ++jj) {
            int row = mt*16 + kg*4 + jj;
            ctxl[row*NFP + (2*w)*16   + col16] = f2bfh(felu(c0[mt][jj]));
            ctxl[row*NFP + (2*w+1)*16 + col16] = f2bfh(felu(c1[mt][jj]));
        }
    __syncthreads();   // B3

    // ---- phase 2: two q-passes; af A-frags straight from global (cached)
    #pragma unroll 1
    for (int q = 0; q < 2; ++q) {
        const int nt0 = 2*w + q;
        const int f   = w*32 + q*16 + col16;
        f32x4 rA[4], zA[4], nA[4], hA[4];
        {
            const float rb = bih[f]     + bhh[f];
            const float zb = bih[F+f]   + bhh[F+f];
            const float nb = bih[2*F+f];
            const float hb = bhh[2*F+f];
            #pragma unroll
            for (int mt = 0; mt < 4; ++mt)
                #pragma unroll
                for (int jj = 0; jj < 4; ++jj) {
                    rA[mt][jj] = rb; zA[mt][jj] = zb;
                    nA[mt][jj] = nb; hA[mt][jj] = hb;
                }
        }
        #pragma unroll 1
        for (int ks = 0; ks < 8; ++ks) {
            bf16x8 bir = *(const bf16x8*)&wsIh[(size_t)(( 0 + nt0)*8 + ks)*512 + lane*8];
            bf16x8 bhr = *(const bf16x8*)&wsHh[(size_t)(( 0 + nt0)*8 + ks)*512 + lane*8];
            bf16x8 biz = *(const bf16x8*)&wsIh[(size_t)((16 + nt0)*8 + ks)*512 + lane*8];
            bf16x8 bhz = *(const bf16x8*)&wsHh[(size_t)((16 + nt0)*8 + ks)*512 + lane*8];
            bf16x8 bin = *(const bf16x8*)&wsIh[(size_t)((32 + nt0)*8 + ks)*512 + lane*8];
            bf16x8 bhn = *(const bf16x8*)&wsHh[(size_t)((32 + nt0)*8 + ks)*512 + lane*8];
            #pragma unroll
            for (int mt = 0; mt < 4; ++mt) {
                bf16x8 ac = *(const bf16x8*)&ctxl[(mt*16 + col16)*NFP + ks*32 + kg*8];
                bf16x8 ah = *(const bf16x8*)&afb[(size_t)(mt*16 + col16)*F + ks*32 + kg*8];
                rA[mt] = __builtin_amdgcn_mfma_f32_16x16x32_bf16(ac, bir, rA[mt], 0, 0, 0);
                rA[mt] = __builtin_amdgcn_mfma_f32_16x16x32_bf16(ah, bhr, rA[mt], 0, 0, 0);
                zA[mt] = __builtin_amdgcn_mfma_f32_16x16x32_bf16(ac, biz, zA[mt], 0, 0, 0);
                zA[mt] = __builtin_amdgcn_mfma_f32_16x16x32_bf16(ah, bhz, zA[mt], 0, 0, 0);
                nA[mt] = __builtin_amdgcn_mfma_f32_16x16x32_bf16(ac, bin, nA[mt], 0, 0, 0);
                hA[mt] = __builtin_amdgcn_mfma_f32_16x16x32_bf16(ah, bhn, hA[mt], 0, 0, 0);
            }
        }
        #pragma unroll
        for (int mt = 0; mt < 4; ++mt)
            #pragma unroll
            for (int jj = 0; jj < 4; ++jj) {
                int a = mt*16 + kg*4 + jj;
                float r = sigm(rA[mt][jj]);
                float z = sigm(zA[mt][jj]);
                float n = ftanh(nA[mt][jj] + r*hA[mt][jj]);
                float h = bf2f(afb[(size_t)a*F + f]);
                float o = n + z*(h - n);          // (1-z)*n + z*h
                __builtin_nontemporal_store(fmaxf(o, 0.f), &out[(size_t)(g0+a)*F + f]);
            }
    }
}

extern "C" void kernel_launch(void* const* d_in, const int* in_sizes, int n_in,
                              void* d_out, int out_size, void* d_ws, size_t ws_size,
                              hipStream_t stream) {
    const float* atom_list = (const float*)d_in[0];
    const float* bond_list = (const float*)d_in[1];
    const int*   adeg      = (const int*)  d_in[2];
    const int*   bdeg      = (const int*)  d_in[3];
    const float* W_atom  = (const float*)d_in[5];
    const float* b_atom  = (const float*)d_in[6];
    const float* W_nbr   = (const float*)d_in[7];
    const float* b_nbr   = (const float*)d_in[8];
    const float* W_align = (const float*)d_in[9];
    const float* b_align = (const float*)d_in[10];
    const float* W_att   = (const float*)d_in[11];
    const float* b_att   = (const float*)d_in[12];
    const float* W_ih    = (const float*)d_in[13];
    const float* b_ih    = (const float*)d_in[14];
    const float* W_hh    = (const float*)d_in[15];
    const float* b_hh    = (const float*)d_in[16];
    float* out = (float*)d_out;

    unsigned short* wsu   = (unsigned short*)d_ws;
    float* sumaw          = (float*)((char*)d_ws + WS_SUM);
    unsigned short* af_bf = (unsigned short*)((char*)d_ws + WS_AF);
    unsigned short* wn    = (unsigned short*)((char*)d_ws + WS_WN);

    p0_prep<<<1936, 256, 0, stream>>>(W_atom, W_nbr, W_att, W_ih, W_hh, W_align, wsu);
    k2_nbr<<<(Bsz*Lm)/TB, NT2, 0, stream>>>(atom_list, bond_list, adeg, bdeg,
                                            W_align, b_align, b_atom, b_nbr,
                                            wsu, af_bf, wn, sumaw);
    k4_gru<<<(Bsz*Lm)/K4A, NTK4, 0, stream>>>(wsu, wn, af_bf, sumaw,
                                              b_att, b_ih, b_hh, out);
}

// Round 19
// 166.741 us; speedup vs baseline: 1.2881x; 1.2881x over previous
//
#include <hip/hip_runtime.h>
#include <hip/hip_bf16.h>
#include <math.h>

#define Bsz 512
#define Lm  128
#define Mn  6
#define AD  39
#define BDm 10
#define KN  49          // AD+BDm
#define F   256
#define TB  16
#define NR  96          // TB*Mn
#define NFP 264         // padded row stride (ushorts)
#define ANP 72          // staging row stride (ushorts), K padded to 64

// ws byte offsets
#define WS_WATM 0
#define WS_WNBR 32768
#define WS_WATT 65536
#define WS_WIH  196608
#define WS_WHH  589824
#define WS_WALN 983040
#define WS_SUM  991232
#define WS_AF   1253376
#define WS_WN   34807808

typedef __attribute__((ext_vector_type(8))) short bf16x8;
typedef __attribute__((ext_vector_type(4))) float f32x4;
typedef __attribute__((ext_vector_type(4))) unsigned int u32x4;

__device__ __forceinline__ float lrelu(float x){ return x > 0.0f ? x : 0.01f*x; }
__device__ __forceinline__ float sigm(float x){
    return __builtin_amdgcn_rcpf(1.0f + __expf(-x));
}
__device__ __forceinline__ float ftanh(float x){
    float xc = fminf(fmaxf(x, -15.f), 15.f);
    float e  = __expf(2.0f*xc);
    return 1.0f - 2.0f*__builtin_amdgcn_rcpf(e + 1.0f);
}
__device__ __forceinline__ float felu(float x){ return x > 0.f ? x : (__expf(x) - 1.0f); }

__device__ __forceinline__ unsigned short f2bfh(float f){
    __hip_bfloat16 h = __float2bfloat16(f);
    unsigned short s;
    __builtin_memcpy(&s, &h, 2);
    return s;
}
__device__ __forceinline__ unsigned int pack2bf(float lo, float hi){
    float2 f2; f2.x = lo; f2.y = hi;
    __hip_bfloat162 h2 = __float22bfloat162_rn(f2);
    unsigned int u;
    __builtin_memcpy(&u, &h2, 4);
    return u;
}
__device__ __forceinline__ float bf2f(unsigned short h){
    unsigned int u = ((unsigned int)h)<<16;
    return __builtin_bit_cast(float, u);
}

// ---------------- P0: weights -> bf16 fragment-major ----------------
__global__ __launch_bounds__(256)
void p0_prep(const float* __restrict__ Watm, const float* __restrict__ Wnbr,
             const float* __restrict__ Watt, const float* __restrict__ Wih,
             const float* __restrict__ Whh,  const float* __restrict__ Waln,
             unsigned short* __restrict__ ws)
{
    int id = blockIdx.x*256 + threadIdx.x;
    if (id >= 968*512) return;
    int T = id >> 9, e = id & 511;
    int lane = e >> 3, j = e & 7;
    int col16 = lane & 15, kg = lane >> 4;
    float v; unsigned short* dst;
    if (T < 32) {                 // W_atom [256][39], pad 64
        int nt = T >> 1, ks = T & 1;
        int k = ks*32 + kg*8 + j;
        v = (k < AD) ? Watm[(nt*16 + col16)*AD + k] : 0.0f;
        dst = ws + (WS_WATM>>1) + (size_t)T*512 + e;
    } else if (T < 64) {          // W_nbr [256][49], pad 64
        int T2 = T - 32;
        int nt = T2 >> 1, ks = T2 & 1;
        int k = ks*32 + kg*8 + j;
        v = (k < KN) ? Wnbr[(nt*16 + col16)*KN + k] : 0.0f;
        dst = ws + (WS_WNBR>>1) + (size_t)T2*512 + e;
    } else if (T < 192) {         // W_att [256][256]
        int T2 = T - 64;
        int nt = T2 >> 3, ks = T2 & 7;
        v = Watt[(nt*16 + col16)*F + ks*32 + kg*8 + j];
        dst = ws + (WS_WATT>>1) + (size_t)T2*512 + e;
    } else if (T < 576) {         // W_ih [768][256]
        int T3 = T - 192;
        int nt = T3 >> 3, ks = T3 & 7;
        v = Wih[(nt*16 + col16)*F + ks*32 + kg*8 + j];
        dst = ws + (WS_WIH>>1) + (size_t)T3*512 + e;
    } else if (T < 960) {         // W_hh [768][256]
        int T4 = T - 576;
        int nt = T4 >> 3, ks = T4 & 7;
        v = Whh[(nt*16 + col16)*F + ks*32 + kg*8 + j];
        dst = ws + (WS_WHH>>1) + (size_t)T4*512 + e;
    } else {                      // walign2 b-frag: col 0 = Walign[256+k]
        int ks = T - 960;
        v = (col16 == 0) ? Waln[F + ks*32 + kg*8 + j] : 0.0f;
        dst = ws + (WS_WALN>>1) + (size_t)ks*512 + e;
    }
    *dst = f2bfh(v);
}

// ---------------- K2: 8 waves; atom+neighbor MFMA, af store, MFMA nscore, softmax, wn ----------------
#define NT2 512
__global__ __launch_bounds__(NT2, 6)
void k2_nbr(const float* __restrict__ atom, const float* __restrict__ bond,
            const int* __restrict__ adeg_g, const int* __restrict__ bdeg_g,
            const float* __restrict__ Walign, const float* __restrict__ balign,
            const float* __restrict__ batom,  const float* __restrict__ bnbr,
            const unsigned short* __restrict__ ws,
            unsigned short* __restrict__ af_g,
            unsigned short* __restrict__ wn_g, float* __restrict__ sumaw_g)
{
    __shared__ alignas(16) unsigned short nfl[NR*NFP];   // staging overlaid
    __shared__ float ascl[TB];
    __shared__ float nscl[NR];
    __shared__ float awl[NR];
    __shared__ int   adeg[NR];
    __shared__ int   bdeg[NR];
    unsigned short* stg = nfl;   // [112][ANP]: rows 0-15 own atoms, 16-111 neighbors

    const int t  = threadIdx.x;
    const int g0 = blockIdx.x*TB;
    const int molbase = (g0/Lm)*Lm;
    const int w = t >> 6, lane = t & 63;
    const int col16 = lane & 15, kg = lane >> 4;

    bf16x8 batmf[2][2], bnbrf[2][2];   // [j][ks]
    #pragma unroll
    for (int j = 0; j < 2; ++j)
        #pragma unroll
        for (int ks = 0; ks < 2; ++ks) {
            batmf[j][ks] = *(const bf16x8*)&ws[(WS_WATM>>1) + (size_t)((2*w+j)*2 + ks)*512 + lane*8];
            bnbrf[j][ks] = *(const bf16x8*)&ws[(WS_WNBR>>1) + (size_t)((2*w+j)*2 + ks)*512 + lane*8];
        }

    if (t < NR) {
        adeg[t] = adeg_g[(size_t)g0*Mn + t];
        bdeg[t] = bdeg_g[(size_t)g0*Mn + t];
    }
    if (t < TB) ascl[t] = 0.f;
    __syncthreads();   // B0

    for (int i = t; i < 112*32; i += NT2) {
        int r = i >> 5, d0 = (i & 31)*2;
        float v0, v1;
        if (r < TB) {
            const float* src = atom + (size_t)(g0+r)*AD;
            v0 = (d0   < AD) ? src[d0]   : 0.f;
            v1 = (d0+1 < AD) ? src[d0+1] : 0.f;
        } else {
            int rr = r - TB;
            const float* asrc = atom + (size_t)(molbase + adeg[rr])*AD;
            const float* bsrc = bond + (size_t)(molbase + bdeg[rr])*BDm;
            int d1 = d0+1;
            v0 = (d0 < AD) ? asrc[d0] : ((d0 < KN) ? bsrc[d0-AD] : 0.f);
            v1 = (d1 < AD) ? asrc[d1] : ((d1 < KN) ? bsrc[d1-AD] : 0.f);
        }
        *(unsigned int*)&stg[r*ANP + d0] = pack2bf(v0, v1);
    }
    __syncthreads();   // B1

    // ---- atom MFMA -> af (global bf16, nt) + ascore
    {
        f32x4 acc[2];
        #pragma unroll
        for (int j = 0; j < 2; ++j) acc[j] = (f32x4){0.f,0.f,0.f,0.f};
        #pragma unroll
        for (int ks = 0; ks < 2; ++ks) {
            bf16x8 a = *(const bf16x8*)&stg[col16*ANP + ks*32 + kg*8];
            #pragma unroll
            for (int j = 0; j < 2; ++j)
                acc[j] = __builtin_amdgcn_mfma_f32_16x16x32_bf16(a, batmf[j][ks], acc[j], 0, 0, 0);
        }
        float ps[4] = {0.f,0.f,0.f,0.f};
        #pragma unroll
        for (int j = 0; j < 2; ++j) {
            const int col = (2*w+j)*16 + col16;
            const float bb  = batom[col];
            const float wal = Walign[col];
            #pragma unroll
            for (int jj = 0; jj < 4; ++jj) {
                float v = lrelu(acc[j][jj] + bb);
                __builtin_nontemporal_store(f2bfh(v), &af_g[(size_t)(g0 + kg*4 + jj)*F + col]);
                ps[jj] += v*wal;
            }
        }
        #pragma unroll
        for (int jj = 0; jj < 4; ++jj) {
            float p = ps[jj];
            p += __shfl_xor(p, 1); p += __shfl_xor(p, 2);
            p += __shfl_xor(p, 4); p += __shfl_xor(p, 8);
            if (col16 == 0) atomicAdd(&ascl[kg*4 + jj], p);
        }
    }

    // ---- neighbor MFMA
    f32x4 acc[6][2];
    #pragma unroll
    for (int mt = 0; mt < 6; ++mt)
        #pragma unroll
        for (int j = 0; j < 2; ++j) acc[mt][j] = (f32x4){0.f,0.f,0.f,0.f};
    __builtin_amdgcn_s_setprio(1);
    #pragma unroll
    for (int ks = 0; ks < 2; ++ks) {
        #pragma unroll
        for (int mt = 0; mt < 6; ++mt) {
            bf16x8 a = *(const bf16x8*)&stg[(TB + mt*16 + col16)*ANP + ks*32 + kg*8];
            #pragma unroll
            for (int j = 0; j < 2; ++j)
                acc[mt][j] = __builtin_amdgcn_mfma_f32_16x16x32_bf16(a, bnbrf[j][ks], acc[mt][j], 0, 0, 0);
        }
    }
    __builtin_amdgcn_s_setprio(0);
    __syncthreads();   // B2

    #pragma unroll
    for (int mt = 0; mt < 6; ++mt)
        #pragma unroll
        for (int j = 0; j < 2; ++j) {
            const int col = (2*w+j)*16 + col16;
            const float bnb = bnbr[col];
            #pragma unroll
            for (int jj = 0; jj < 4; ++jj)
                nfl[(mt*16 + kg*4 + jj)*NFP + col] = f2bfh(lrelu(acc[mt][j][jj] + bnb));
        }
    __syncthreads();   // B3

    // ---- nscore via MFMA (B col0-only frag); waves 0..5
    if (w < 6) {
        const int mt = w;
        f32x4 ns = {0.f,0.f,0.f,0.f};
        #pragma unroll
        for (int ks = 0; ks < 8; ++ks) {
            bf16x8 a = *(const bf16x8*)&nfl[(mt*16 + col16)*NFP + ks*32 + kg*8];
            bf16x8 b = *(const bf16x8*)&ws[(WS_WALN>>1) + (size_t)ks*512 + lane*8];
            ns = __builtin_amdgcn_mfma_f32_16x16x32_bf16(a, b, ns, 0, 0, 0);
        }
        if (col16 == 0) {
            #pragma unroll
            for (int jj = 0; jj < 4; ++jj) nscl[mt*16 + kg*4 + jj] = ns[jj];
        }
    }
    __syncthreads();   // B4

    if (t < TB) {
        const float ba = balign[0];
        const float as = ascl[t];
        float sc[Mn], msk[Mn];
        float mx = -1e30f;
        #pragma unroll
        for (int m = 0; m < Mn; ++m) {
            int pad = (adeg[t*Mn+m] == Lm-1);
            float s = lrelu(as + nscl[t*Mn+m] + ba) + (pad ? -9e8f : 0.0f);
            msk[m] = pad ? 0.f : 1.f;
            sc[m] = s; mx = fmaxf(mx, s);
        }
        float sum = 0.f;
        #pragma unroll
        for (int m = 0; m < Mn; ++m) { sc[m] = __expf(sc[m]-mx); sum += sc[m]; }
        const float inv = __builtin_amdgcn_rcpf(sum);
        float sa = 0.f;
        #pragma unroll
        for (int m = 0; m < Mn; ++m) { float v = sc[m]*inv*msk[m]; awl[t*Mn+m] = v; sa += v; }
        sumaw_g[g0 + t] = sa;
    }
    __syncthreads();   // B5

    // wn[a][:] = sum_m aw*nf  (nt store: read exactly once by k4 phase1)
    {
        const int a = t & 15, cg = t >> 4;
        float o[8] = {0,0,0,0,0,0,0,0};
        #pragma unroll
        for (int m = 0; m < Mn; ++m) {
            const float aw = awl[a*Mn + m];
            u32x4 v = *(const u32x4*)&nfl[(a*Mn+m)*NFP + cg*8];
            o[0] += aw*__builtin_bit_cast(float, v.x<<16);
            o[1] += aw*__builtin_bit_cast(float, v.x & 0xffff0000u);
            o[2] += aw*__builtin_bit_cast(float, v.y<<16);
            o[3] += aw*__builtin_bit_cast(float, v.y & 0xffff0000u);
            o[4] += aw*__builtin_bit_cast(float, v.z<<16);
            o[5] += aw*__builtin_bit_cast(float, v.z & 0xffff0000u);
            o[6] += aw*__builtin_bit_cast(float, v.w<<16);
            o[7] += aw*__builtin_bit_cast(float, v.w & 0xffff0000u);
        }
        u32x4 pv;
        pv.x = pack2bf(o[0], o[1]);
        pv.y = pack2bf(o[2], o[3]);
        pv.z = pack2bf(o[4], o[5]);
        pv.w = pack2bf(o[6], o[7]);
        __builtin_nontemporal_store(pv, (u32x4*)&wn_g[(size_t)(g0+a)*F + cg*8]);
    }
}

// ---------------- K4: ctx GEMM + q-split GRU GEMM + gates (R17 form + setprio) ----------------
// afl staged in LDS (R18 proved global A-frags in the inner loop regress).
// q-split (64 acc VGPRs) + unroll-1 ks loops bounds live B-frags (no spill).
// NO min-waves bound (R6/R9); NO full unroll (R11/R12).
#define NTK4 512
#define K4A  64
__global__ __launch_bounds__(NTK4)
void k4_gru(const unsigned short* __restrict__ ws,
            const unsigned short* __restrict__ wn_g,
            const unsigned short* __restrict__ af_g,
            const float* __restrict__ sumaw_g,
            const float* __restrict__ batt,
            const float* __restrict__ bih, const float* __restrict__ bhh,
            float* __restrict__ out)
{
    __shared__ alignas(16) unsigned short wnl[K4A*NFP];   // ctxl overlays after phase1
    __shared__ alignas(16) unsigned short afl[K4A*NFP];
    __shared__ float sumawl[K4A];
    const int t  = threadIdx.x;
    const int g0 = blockIdx.x*K4A;

    for (int i = t; i < K4A*32*2; i += NTK4) {
        int m = i >> 11;
        int ii = i & 2047;
        int row = ii >> 5, cg = ii & 31;
        const unsigned short* src = m ? af_g : wn_g;
        unsigned short* dst = m ? afl : wnl;
        u32x4 v = __builtin_nontemporal_load((const u32x4*)&src[(size_t)(g0+row)*F + cg*8]);
        *(u32x4*)&dst[row*NFP + cg*8] = v;
    }
    if (t < K4A) sumawl[t] = sumaw_g[g0 + t];
    __syncthreads();   // B1

    const int w = t >> 6, lane = t & 63;
    const int col16 = lane & 15, kg = lane >> 4;
    const unsigned short* wsAtt = ws + (WS_WATT>>1);
    const unsigned short* wsIh  = ws + (WS_WIH>>1);
    const unsigned short* wsHh  = ws + (WS_WHH>>1);

    // ---- phase 1: ctx = elu(wn @ Watt^T + b_att*sumaw); wave w -> nt {2w, 2w+1}
    f32x4 c0[4], c1[4];
    {
        const float bb0 = batt[(2*w)*16   + col16];
        const float bb1 = batt[(2*w+1)*16 + col16];
        #pragma unroll
        for (int mt = 0; mt < 4; ++mt)
            #pragma unroll
            for (int jj = 0; jj < 4; ++jj) {
                float sa = sumawl[mt*16 + kg*4 + jj];
                c0[mt][jj] = bb0*sa; c1[mt][jj] = bb1*sa;
            }
        __builtin_amdgcn_s_setprio(1);
        #pragma unroll 2
        for (int ks = 0; ks < 8; ++ks) {
            bf16x8 b0 = *(const bf16x8*)&wsAtt[(size_t)((2*w)*8   + ks)*512 + lane*8];
            bf16x8 b1 = *(const bf16x8*)&wsAtt[(size_t)((2*w+1)*8 + ks)*512 + lane*8];
            #pragma unroll
            for (int mt = 0; mt < 4; ++mt) {
                bf16x8 a = *(const bf16x8*)&wnl[(mt*16 + col16)*NFP + ks*32 + kg*8];
                c0[mt] = __builtin_amdgcn_mfma_f32_16x16x32_bf16(a, b0, c0[mt], 0, 0, 0);
                c1[mt] = __builtin_amdgcn_mfma_f32_16x16x32_bf16(a, b1, c1[mt], 0, 0, 0);
            }
        }
        __builtin_amdgcn_s_setprio(0);
    }
    __syncthreads();   // B2
    unsigned short* ctxl = wnl;
    #pragma unroll
    for (int mt = 0; mt < 4; ++mt)
        #pragma unroll
        for (int jj = 0; jj < 4; ++jj) {
            int row = mt*16 + kg*4 + jj;
            ctxl[row*NFP + (2*w)*16   + col16] = f2bfh(felu(c0[mt][jj]));
            ctxl[row*NFP + (2*w+1)*16 + col16] = f2bfh(felu(c1[mt][jj]));
        }
    __syncthreads();   // B3

    // ---- phase 2: two q-passes; ks loop NOT unrolled (bounds live B-frags)
    #pragma unroll 1
    for (int q = 0; q < 2; ++q) {
        const int nt0 = 2*w + q;
        const int f   = w*32 + q*16 + col16;
        f32x4 rA[4], zA[4], nA[4], hA[4];
        {
            const float rb = bih[f]     + bhh[f];
            const float zb = bih[F+f]   + bhh[F+f];
            const float nb = bih[2*F+f];
            const float hb = bhh[2*F+f];
            #pragma unroll
            for (int mt = 0; mt < 4; ++mt)
                #pragma unroll
                for (int jj = 0; jj < 4; ++jj) {
                    rA[mt][jj] = rb; zA[mt][jj] = zb;
                    nA[mt][jj] = nb; hA[mt][jj] = hb;
                }
        }
        __builtin_amdgcn_s_setprio(1);
        #pragma unroll 1
        for (int ks = 0; ks < 8; ++ks) {
            bf16x8 bir = *(const bf16x8*)&wsIh[(size_t)(( 0 + nt0)*8 + ks)*512 + lane*8];
            bf16x8 bhr = *(const bf16x8*)&wsHh[(size_t)(( 0 + nt0)*8 + ks)*512 + lane*8];
            bf16x8 biz = *(const bf16x8*)&wsIh[(size_t)((16 + nt0)*8 + ks)*512 + lane*8];
            bf16x8 bhz = *(const bf16x8*)&wsHh[(size_t)((16 + nt0)*8 + ks)*512 + lane*8];
            bf16x8 bin = *(const bf16x8*)&wsIh[(size_t)((32 + nt0)*8 + ks)*512 + lane*8];
            bf16x8 bhn = *(const bf16x8*)&wsHh[(size_t)((32 + nt0)*8 + ks)*512 + lane*8];
            #pragma unroll
            for (int mt = 0; mt < 4; ++mt) {
                bf16x8 ac = *(const bf16x8*)&ctxl[(mt*16 + col16)*NFP + ks*32 + kg*8];
                bf16x8 ah = *(const bf16x8*)&afl [(mt*16 + col16)*NFP + ks*32 + kg*8];
                rA[mt] = __builtin_amdgcn_mfma_f32_16x16x32_bf16(ac, bir, rA[mt], 0, 0, 0);
                rA[mt] = __builtin_amdgcn_mfma_f32_16x16x32_bf16(ah, bhr, rA[mt], 0, 0, 0);
                zA[mt] = __builtin_amdgcn_mfma_f32_16x16x32_bf16(ac, biz, zA[mt], 0, 0, 0);
                zA[mt] = __builtin_amdgcn_mfma_f32_16x16x32_bf16(ah, bhz, zA[mt], 0, 0, 0);
                nA[mt] = __builtin_amdgcn_mfma_f32_16x16x32_bf16(ac, bin, nA[mt], 0, 0, 0);
                hA[mt] = __builtin_amdgcn_mfma_f32_16x16x32_bf16(ah, bhn, hA[mt], 0, 0, 0);
            }
        }
        __builtin_amdgcn_s_setprio(0);
        #pragma unroll
        for (int mt = 0; mt < 4; ++mt)
            #pragma unroll
            for (int jj = 0; jj < 4; ++jj) {
                int a = mt*16 + kg*4 + jj;
                float r = sigm(rA[mt][jj]);
                float z = sigm(zA[mt][jj]);
                float n = ftanh(nA[mt][jj] + r*hA[mt][jj]);
                float h = bf2f(afl[a*NFP + f]);
                float o = n + z*(h - n);          // (1-z)*n + z*h
                __builtin_nontemporal_store(fmaxf(o, 0.f), &out[(size_t)(g0+a)*F + f]);
            }
    }
}

extern "C" void kernel_launch(void* const* d_in, const int* in_sizes, int n_in,
                              void* d_out, int out_size, void* d_ws, size_t ws_size,
                              hipStream_t stream) {
    const float* atom_list = (const float*)d_in[0];
    const float* bond_list = (const float*)d_in[1];
    const int*   adeg      = (const int*)  d_in[2];
    const int*   bdeg      = (const int*)  d_in[3];
    const float* W_atom  = (const float*)d_in[5];
    const float* b_atom  = (const float*)d_in[6];
    const float* W_nbr   = (const float*)d_in[7];
    const float* b_nbr   = (const float*)d_in[8];
    const float* W_align = (const float*)d_in[9];
    const float* b_align = (const float*)d_in[10];
    const float* W_att   = (const float*)d_in[11];
    const float* b_att   = (const float*)d_in[12];
    const float* W_ih    = (const float*)d_in[13];
    const float* b_ih    = (const float*)d_in[14];
    const float* W_hh    = (const float*)d_in[15];
    const float* b_hh    = (const float*)d_in[16];
    float* out = (float*)d_out;

    unsigned short* wsu   = (unsigned short*)d_ws;
    float* sumaw          = (float*)((char*)d_ws + WS_SUM);
    unsigned short* af_bf = (unsigned short*)((char*)d_ws + WS_AF);
    unsigned short* wn    = (unsigned short*)((char*)d_ws + WS_WN);

    p0_prep<<<1936, 256, 0, stream>>>(W_atom, W_nbr, W_att, W_ih, W_hh, W_align, wsu);
    k2_nbr<<<(Bsz*Lm)/TB, NT2, 0, stream>>>(atom_list, bond_list, adeg, bdeg,
                                            W_align, b_align, b_atom, b_nbr,
                                            wsu, af_bf, wn, sumaw);
    k4_gru<<<(Bsz*Lm)/K4A, NTK4, 0, stream>>>(wsu, wn, af_bf, sumaw,
                                              b_att, b_ih, b_hh, out);
}